// Round 8
// baseline (395.513 us; speedup 1.0000x reference)
//
#include <hip/hip_runtime.h>
#include <hip/hip_bf16.h>
#include <cstddef>

namespace {

constexpr int N = 100000;
constexpr int IN = 256;
constexpr int H = 128;
constexpr int R = 5;
constexpr int E = 100000;
constexpr int RE = R * E;
constexpr int NB = (N + 255) / 256;  // scan blocks

using short8 = __attribute__((ext_vector_type(8))) short;
using f32x4 = __attribute__((ext_vector_type(4))) float;

__device__ __forceinline__ float b2f(unsigned int u16) {
  union { unsigned int i; float f; } v;
  v.i = u16 << 16;
  return v.f;
}
__device__ __forceinline__ unsigned short f2b(float f) {
  union { float f; unsigned int u; } v;
  v.f = f;
  unsigned int r = v.u + 0x7fffu + ((v.u >> 16) & 1u);
  return (unsigned short)(r >> 16);
}

__global__ void deg_count(const int* __restrict__ dst, float* __restrict__ deg,
                          int* __restrict__ degtot) {
  int i = blockIdx.x * 256 + threadIdx.x;
  if (i < RE) {
    int d = dst[i];
    atomicAdd(&deg[(i / E) * N + d], 1.0f);
    atomicAdd(&degtot[d], 1);
  }
}

__global__ void inv_deg_k(float* __restrict__ deg) {
  int i = blockIdx.x * 256 + threadIdx.x;
  if (i < R * N) deg[i] = 1.0f / fmaxf(deg[i], 1.0f);
}

// ---- exclusive prefix scan over degtot ----
__global__ void scan_blk(const int* __restrict__ in, int* __restrict__ part,
                         int* __restrict__ bsum, int n) {
  __shared__ int tmp[256];
  int tid = threadIdx.x;
  int gid = blockIdx.x * 256 + tid;
  int v = (gid < n) ? in[gid] : 0;
  tmp[tid] = v;
  __syncthreads();
  for (int o = 1; o < 256; o <<= 1) {
    int t = (tid >= o) ? tmp[tid - o] : 0;
    __syncthreads();
    tmp[tid] += t;
    __syncthreads();
  }
  if (gid < n) part[gid] = tmp[tid] - v;
  if (tid == 255) bsum[blockIdx.x] = tmp[255];
}

__global__ void scan_top(const int* __restrict__ bsum, int* __restrict__ bscan, int nb) {
  __shared__ int tmp[512];
  int tid = threadIdx.x;
  int v = (tid < nb) ? bsum[tid] : 0;
  tmp[tid] = v;
  __syncthreads();
  for (int o = 1; o < 512; o <<= 1) {
    int t = (tid >= o) ? tmp[tid - o] : 0;
    __syncthreads();
    tmp[tid] += t;
    __syncthreads();
  }
  if (tid < nb) bscan[tid] = tmp[tid] - v;
}

__global__ void scan_add(int* __restrict__ part, const int* __restrict__ bscan, int n) {
  int gid = blockIdx.x * 256 + threadIdx.x;
  if (gid < n) part[gid] += bscan[gid >> 8];
}

// counting-sort edges; per-edge fp32 coef*invdeg pairs for both layers
__global__ void fill_csr(const int* __restrict__ src, const int* __restrict__ dst,
                         const float* __restrict__ coef1, const float* __restrict__ coef2,
                         const float* __restrict__ invdeg, const int* __restrict__ off,
                         int* __restrict__ cursor, int* __restrict__ esrc,
                         float2* __restrict__ ecA, float2* __restrict__ ecB) {
  int i = blockIdx.x * 256 + threadIdx.x;
  if (i >= RE) return;
  int r = i / E;
  int d = dst[i];
  int slot = off[d] + atomicAdd(&cursor[d], 1);
  float id = invdeg[r * N + d];
  esrc[slot] = src[i];
  ecA[slot] = make_float2(coef1[2 * r] * id, coef1[2 * r + 1] * id);
  ecB[slot] = make_float2(coef2[2 * r] * id, coef2[2 * r + 1] * id);
}

// all three weight packs in one kernel (bf16 MFMA B-fragment order)
__global__ void pack_all(const float* __restrict__ w_embed,
                         const float* __restrict__ basis1,
                         const float* __restrict__ basis2,
                         unsigned short* __restrict__ wp1,
                         unsigned short* __restrict__ wpB1,
                         unsigned short* __restrict__ wpB2) {
  int i = blockIdx.x * 256 + threadIdx.x;
  if (i < 32768) {
    int ii = i & 7, lane = (i >> 3) & 63, fb = i >> 9;
    int kc = fb >> 3, ct = fb & 7;
    int k = kc * 32 + ((lane >> 4) << 3) + ii, col = (ct << 4) + (lane & 15);
    wp1[i] = f2b(w_embed[(size_t)k * 128 + col]);
  } else if (i < 65536) {
    int j = i - 32768;
    int ii = j & 7, lane = (j >> 3) & 63, fb = j >> 9;
    int kc = fb >> 3, ct = fb & 7;
    int k = kc * 32 + ((lane >> 4) << 3) + ii, col = (ct << 4) + (lane & 15);
    wpB1[j] = f2b(basis1[(size_t)k * 128 + col]);
  } else if (i < 65536 + 4096) {
    int j = i - 65536;
    int ii = j & 7, lane = (j >> 3) & 63, fb = j >> 9;
    int kc = fb >> 1, ct = fb & 1;
    int k = kc * 32 + ((lane >> 4) << 3) + ii;
    wpB2[j] = f2b(basis2[((size_t)ct * 128 + k) * 16 + (lane & 15)]);
  }
}

// h = x @ w_embed + b_embed.  Register-staged A: all 16 float4 loads issued
// up front (incremental vmcnt pipelining), no LDS, no barriers. 16 rows/wave.
__global__ __launch_bounds__(256) void gemm_embed(
    const float* __restrict__ x, const unsigned short* __restrict__ wpack,
    const float* __restrict__ bias, unsigned short* __restrict__ C) {
  const int tid = threadIdx.x, lane = tid & 63;
  const int wave = (blockIdx.x * 256 + tid) >> 6;
  const int base = wave * 16;
  if (base >= N) return;               // N%16==0
  const int r = lane & 15, g = lane >> 4;
  const short8* wfrag = (const short8*)wpack;

  const float* arow = x + (size_t)(base + r) * IN + g * 8;
  float4 a[8][2];
#pragma unroll
  for (int kc = 0; kc < 8; ++kc) {
    a[kc][0] = *(const float4*)(arow + kc * 32);
    a[kc][1] = *(const float4*)(arow + kc * 32 + 4);
  }

  f32x4 acc[8];
#pragma unroll
  for (int ct = 0; ct < 8; ++ct) acc[ct] = (f32x4){0.f, 0.f, 0.f, 0.f};

#pragma unroll
  for (int kc = 0; kc < 8; ++kc) {
    short8 af;
    af[0] = (short)f2b(a[kc][0].x); af[1] = (short)f2b(a[kc][0].y);
    af[2] = (short)f2b(a[kc][0].z); af[3] = (short)f2b(a[kc][0].w);
    af[4] = (short)f2b(a[kc][1].x); af[5] = (short)f2b(a[kc][1].y);
    af[6] = (short)f2b(a[kc][1].z); af[7] = (short)f2b(a[kc][1].w);
#pragma unroll
    for (int ct = 0; ct < 8; ++ct)
      acc[ct] = __builtin_amdgcn_mfma_f32_16x16x32_bf16(
          af, wfrag[(kc * 8 + ct) * 64 + lane], acc[ct], 0, 0, 0);
  }

#pragma unroll
  for (int ct = 0; ct < 8; ++ct) {
    int col = ct * 16 + r;
    float bs = bias[col];
#pragma unroll
    for (int i = 0; i < 4; ++i)
      C[(size_t)(base + g * 4 + i) * H + col] = f2b(acc[ct][i] + bs);
  }
}

// Fused: h2 = relu(u @ basis1 + bias1); q = h2 @ wp2.  Register-staged A;
// only the per-wave h2-transpose tile lives in LDS.
__global__ __launch_bounds__(256) void gemm_fused(
    const unsigned short* __restrict__ u, const unsigned short* __restrict__ wp1,
    const float* __restrict__ bias1, const unsigned short* __restrict__ wp2,
    unsigned short* __restrict__ q) {
  __shared__ __align__(16) unsigned short hl[4][16][136];  // +8sh pad
  const int tid = threadIdx.x, lane = tid & 63, wv = tid >> 6;
  const int wave = (blockIdx.x * 256 + tid) >> 6;
  const int base = wave * 16;
  if (base >= N) return;
  const int r = lane & 15, g = lane >> 4;
  const short8* wf1 = (const short8*)wp1;
  const short8* wf2 = (const short8*)wp2;

  const unsigned short* arow = u + (size_t)(base + r) * 256 + g * 8;
  short8 a[8];
#pragma unroll
  for (int kc = 0; kc < 8; ++kc) a[kc] = *(const short8*)(arow + kc * 32);

  f32x4 acc[8];
#pragma unroll
  for (int ct = 0; ct < 8; ++ct) acc[ct] = (f32x4){0.f, 0.f, 0.f, 0.f};

#pragma unroll
  for (int kc = 0; kc < 8; ++kc) {
#pragma unroll
    for (int ct = 0; ct < 8; ++ct)
      acc[ct] = __builtin_amdgcn_mfma_f32_16x16x32_bf16(
          a[kc], wf1[(kc * 8 + ct) * 64 + lane], acc[ct], 0, 0, 0);
  }

  // bias + relu -> per-wave LDS h2 tile
#pragma unroll
  for (int ct = 0; ct < 8; ++ct) {
    int col = ct * 16 + r;
    float bs = bias1[col];
#pragma unroll
    for (int i = 0; i < 4; ++i)
      hl[wv][g * 4 + i][col] = f2b(fmaxf(acc[ct][i] + bs, 0.f));
  }

  // same-wave LDS produce->consume fence (rule #18)
  asm volatile("s_waitcnt lgkmcnt(0)" ::: "memory");
  __builtin_amdgcn_sched_barrier(0);

  f32x4 acc2[2];
#pragma unroll
  for (int ct = 0; ct < 2; ++ct) acc2[ct] = (f32x4){0.f, 0.f, 0.f, 0.f};

#pragma unroll
  for (int kc = 0; kc < 4; ++kc) {
    short8 af = *(const short8*)&hl[wv][r][kc * 32 + g * 8];
#pragma unroll
    for (int ct = 0; ct < 2; ++ct)
      acc2[ct] = __builtin_amdgcn_mfma_f32_16x16x32_bf16(
          af, wf2[(kc * 2 + ct) * 64 + lane], acc2[ct], 0, 0, 0);
  }

#pragma unroll
  for (int ct = 0; ct < 2; ++ct) {
    int col = ct * 16 + r;
#pragma unroll
    for (int i = 0; i < 4; ++i)
      q[(size_t)(base + g * 4 + i) * 32 + col] = f2b(acc2[ct][i]);
  }
}

// layer-1 gather: one wave per dst node, 2-deep h-row pipeline
__global__ __launch_bounds__(256) void gather1(
    const int* __restrict__ off, const int* __restrict__ degtot,
    const int* __restrict__ esrc, const float2* __restrict__ ecA,
    const unsigned short* __restrict__ hbf, unsigned int* __restrict__ ubf) {
  int wid = blockIdx.x * 4 + (threadIdx.x >> 6);
  int lane = threadIdx.x & 63;
  if (wid >= N) return;
  int start = off[wid];
  int cnt = degtot[wid];
  float u0x = 0.f, u0y = 0.f, u1x = 0.f, u1y = 0.f;
  const unsigned int* hrows = (const unsigned int*)hbf;

  if (cnt == 1) {
    float2 c = ecA[start];
    unsigned int hv = hrows[(size_t)esrc[start] * 64 + lane];
    float hx = b2f(hv & 0xffffu), hy = b2f(hv >> 16);
    u0x = c.x * hx; u0y = c.x * hy; u1x = c.y * hx; u1y = c.y * hy;
  } else if (cnt >= 2) {
    float2 c0 = ecA[start], c1 = ecA[start + 1];
    unsigned int hv0 = hrows[(size_t)esrc[start] * 64 + lane];
    unsigned int hv1 = hrows[(size_t)esrc[start + 1] * 64 + lane];
    for (int j = 2; j < cnt; ++j) {
      float2 cn = ecA[start + j];
      unsigned int hvn = hrows[(size_t)esrc[start + j] * 64 + lane];
      float hx = b2f(hv0 & 0xffffu), hy = b2f(hv0 >> 16);
      u0x = fmaf(c0.x, hx, u0x); u0y = fmaf(c0.x, hy, u0y);
      u1x = fmaf(c0.y, hx, u1x); u1y = fmaf(c0.y, hy, u1y);
      c0 = c1; hv0 = hv1; c1 = cn; hv1 = hvn;
    }
    float hx = b2f(hv0 & 0xffffu), hy = b2f(hv0 >> 16);
    u0x = fmaf(c0.x, hx, u0x); u0y = fmaf(c0.x, hy, u0y);
    u1x = fmaf(c0.y, hx, u1x); u1y = fmaf(c0.y, hy, u1y);
    hx = b2f(hv1 & 0xffffu); hy = b2f(hv1 >> 16);
    u0x = fmaf(c1.x, hx, u0x); u0y = fmaf(c1.x, hy, u0y);
    u1x = fmaf(c1.y, hx, u1x); u1y = fmaf(c1.y, hy, u1y);
  }
  unsigned int* ur = ubf + (size_t)wid * 128;
  ur[lane]      = (unsigned int)f2b(u0x) | ((unsigned int)f2b(u0y) << 16);
  ur[64 + lane] = (unsigned int)f2b(u1x) | ((unsigned int)f2b(u1y) << 16);
}

// layer-2 gather: one wave per node, 4 edges in parallel, xor-reduce.
__global__ __launch_bounds__(256) void gather2(
    const int* __restrict__ off, const int* __restrict__ degtot,
    const int* __restrict__ esrc, const float2* __restrict__ ecB,
    const unsigned short* __restrict__ qbf, const float* __restrict__ bias2,
    float* __restrict__ out) {
  int node = blockIdx.x * 4 + (threadIdx.x >> 6);
  int lane = threadIdx.x & 63;
  if (node >= N) return;
  int e = lane >> 4, k = lane & 15;
  int start = off[node];
  int cnt = degtot[node];
  float acc = 0.f;
  for (int j = e; j < cnt; j += 4) {
    int s = esrc[start + j];
    float2 c = ecB[start + j];
    acc = fmaf(c.x, b2f(qbf[(size_t)s * 32 + k]), acc);
    acc = fmaf(c.y, b2f(qbf[(size_t)s * 32 + 16 + k]), acc);
  }
  acc += __shfl_xor(acc, 16);
  acc += __shfl_xor(acc, 32);
  if (e == 0) out[(size_t)node * 16 + k] = acc + bias2[k];
}

}  // namespace

extern "C" void kernel_launch(void* const* d_in, const int* in_sizes, int n_in,
                              void* d_out, int out_size, void* d_ws, size_t ws_size,
                              hipStream_t stream) {
  const float* x       = (const float*)d_in[0];
  const int*   src     = (const int*)d_in[1];
  const int*   dst     = (const int*)d_in[2];
  const float* w_embed = (const float*)d_in[3];
  const float* b_embed = (const float*)d_in[4];
  const float* basis1  = (const float*)d_in[5];
  const float* coef1   = (const float*)d_in[6];
  const float* bias1   = (const float*)d_in[7];
  const float* basis2  = (const float*)d_in[8];
  const float* coef2   = (const float*)d_in[9];
  const float* bias2   = (const float*)d_in[10];
  float* out = (float*)d_out;

  // ws layout: [invdeg | degtot | cursor] contiguous -> single memset
  float*  invdeg = (float*)d_ws;                       // R*N
  int*    degtot = (int*)(invdeg + (size_t)R * N);     // N
  int*    cursor = degtot + N;                         // N
  int*    off    = cursor + N;                         // N
  int*    bsum   = off + N;                            // 512
  int*    bscan  = bsum + 512;                         // 512
  int*    esrc   = bscan + 512;                        // RE
  float2* ecA    = (float2*)(esrc + RE);               // RE
  float2* ecB    = ecA + RE;                           // RE
  unsigned short* wp1  = (unsigned short*)(ecB + RE);  // 256*128
  unsigned short* wpB1 = wp1 + 256 * 128;              // 256*128
  unsigned short* wpB2 = wpB1 + 256 * 128;             // 128*32
  unsigned short* h_bf = wpB2 + 128 * 32;              // N*128
  unsigned short* u_bf = h_bf + (size_t)N * 128;       // N*256
  unsigned short* q_bf = u_bf + (size_t)N * 256;       // N*32

  dim3 b256(256);
  hipMemsetAsync(invdeg, 0, (size_t)(R * N + 2 * N) * sizeof(float), stream);

  deg_count<<<(RE + 255) / 256, b256, 0, stream>>>(dst, invdeg, degtot);
  inv_deg_k<<<(R * N + 255) / 256, b256, 0, stream>>>(invdeg);
  scan_blk<<<NB, b256, 0, stream>>>(degtot, off, bsum, N);
  scan_top<<<1, dim3(512), 0, stream>>>(bsum, bscan, NB);
  scan_add<<<NB, b256, 0, stream>>>(off, bscan, N);
  fill_csr<<<(RE + 255) / 256, b256, 0, stream>>>(src, dst, coef1, coef2, invdeg,
                                                  off, cursor, esrc, ecA, ecB);
  pack_all<<<(65536 + 4096 + 255) / 256, b256, 0, stream>>>(
      w_embed, basis1, basis2, wp1, wpB1, wpB2);

  int gblocks = (N / 16 + 3) / 4;  // 1563
  // h = x @ w_embed + b_embed   (register-staged, barrier-free)
  gemm_embed<<<gblocks, b256, 0, stream>>>(x, wp1, b_embed, h_bf);
  // u[d] = [sum c0*h[s] | sum c1*h[s]]  (CSR gather, 2-deep pipeline)
  gather1<<<(N + 3) / 4, b256, 0, stream>>>(off, degtot, esrc, ecA, h_bf,
                                            (unsigned int*)u_bf);
  // q = relu(u @ basis1 + bias1) @ wpB2   (fused, h2 on-chip)
  gemm_fused<<<gblocks, b256, 0, stream>>>(u_bf, wpB1, bias1, wpB2, q_bf);
  // out[d][k] = bias2[k] + sum (c0*q[s][k] + c1*q[s][16+k])
  gather2<<<(N + 3) / 4, b256, 0, stream>>>(off, degtot, esrc, ecB, q_bf, bias2, out);
}